// Round 3
// baseline (706.371 us; speedup 1.0000x reference)
//
#include <hip/hip_runtime.h>
#include <hip/hip_fp16.h>
#include <math.h>

#define GRID_R 128
#define DATA_DIM 28
#define PAD_DIM 32
#define NSEG 8
#define SEG_STEPS 32
#define STEP_SIZE 0.001f
#define BG 1.0f

// packed half2 for v_dot2
typedef _Float16 h2f __attribute__((ext_vector_type(2)));

// D = a.x*b.x + a.y*b.y + c (f16 products, f32 accumulate) — one VOP3P instr.
#if __has_builtin(__builtin_amdgcn_fdot2)
__device__ __forceinline__ float fdot2(h2f a, h2f b, float c) {
    return __builtin_amdgcn_fdot2(a, b, c, false);
}
#else
__device__ __forceinline__ float fdot2(h2f a, h2f b, float c) {
    return fmaf((float)a.x, (float)b.x, fmaf((float)a.y, (float)b.y, c));
}
#endif

#if __has_builtin(__builtin_amdgcn_exp2f)
__device__ __forceinline__ float fexp2(float x)    { return __builtin_amdgcn_exp2f(x); }
__device__ __forceinline__ float fexp2neg(float x) { return __builtin_amdgcn_exp2f(-x); }
#else
__device__ __forceinline__ float fexp2(float x) {
    float r; asm("v_exp_f32 %0, %1" : "=v"(r) : "v"(x)); return r;
}
__device__ __forceinline__ float fexp2neg(float x) {
    float r; asm("v_exp_f32 %0, -%1" : "=v"(r) : "v"(x)); return r;
}
#endif

#if __has_builtin(__builtin_amdgcn_rcpf)
__device__ __forceinline__ float frcp(float x) { return __builtin_amdgcn_rcpf(x); }
#else
__device__ __forceinline__ float frcp(float x) {
    float r; asm("v_rcp_f32 %0, %1" : "=v"(r) : "v"(x)); return r;
}
#endif

// ---------------------------------------------------------------------------
// Shared per-step geometry — bit-identical to the verified kernel (voxel
// picks at cell boundaries are rounding-sensitive). flat via exact float fma
// (fx*16384+fy*128+fz < 2^21, exactly representable).
// NOTE: safe for ANY finite t (t past tmax clamps into the boundary voxel,
// produces finite dt) — this is what makes unguarded prefetch legal.
// ---------------------------------------------------------------------------
__device__ __forceinline__ float march_step(
    float t, float ox, float oy, float oz,
    float dx, float dy, float dz,
    float idx, float idy, float idz, int* flat)
{
    float px = (ox + t*dx) * 128.0f;
    float py = (oy + t*dy) * 128.0f;
    float pz = (oz + t*dz) * 128.0f;
    float fx = fminf(fmaxf(floorf(px), 0.0f), 127.0f);
    float fy = fminf(fmaxf(floorf(py), 0.0f), 127.0f);
    float fz = fminf(fmaxf(floorf(pz), 0.0f), 127.0f);
    float ff = fmaf(fx, 16384.0f, fmaf(fy, 128.0f, fz));   // exact, < 2^21
    *flat = (int)ff;
    float cx = px - fx, cy = py - fy, cz = pz - fz;
    float a1x = -cx*idx, a1y = -cy*idy, a1z = -cz*idz;
    float a2x = a1x+idx, a2y = a1y+idy, a2z = a1z+idz;
    float e1 = fminf(fminf(fmaxf(a1x,a2x), fmaxf(a1y,a2y)), fmaxf(a1z,a2z));
    e1 = fminf(e1, 1e9f);
    return e1 * (1.0f/128.0f) + STEP_SIZE;
}

// common ray setup (unchanged)
#define RAY_SETUP(i)                                                          \
    float ox = origins[3*(i)+0], oy = origins[3*(i)+1], oz = origins[3*(i)+2];\
    float dx = dirs_in[3*(i)+0], dy = dirs_in[3*(i)+1], dz = dirs_in[3*(i)+2];\
    float dn = sqrtf(dx*dx + dy*dy + dz*dz);                                  \
    float rdn = 1.0f / dn;                                                    \
    dx *= rdn; dy *= rdn; dz *= rdn;                                          \
    float idx = 1.0f / (dx + 1e-9f);                                          \
    float idy = 1.0f / (dy + 1e-9f);                                          \
    float idz = 1.0f / (dz + 1e-9f);                                          \
    float t1x = -ox*idx, t1y = -oy*idy, t1z = -oz*idz;                        \
    float t2x = t1x+idx, t2y = t1y+idy, t2z = t1z+idz;                        \
    float t0   = fmaxf(fmaxf(fmaxf(fminf(t1x,t2x), fminf(t1y,t2y)), fminf(t1z,t2z)), 0.0f); \
    float tmax = fminf(fminf(fminf(fmaxf(t1x,t2x), fmaxf(t1y,t2y)), fmaxf(t1z,t2z)), 1e9f);

// ---------------------------------------------------------------------------
// Fused pre-pass: geom (blocks [0, nGeomB)) + fp32->fp16 grid convert
// (remaining blocks, 2 threads/voxel for coalescing: 56B in / 32B out per
// lane, all 16B-aligned).
//
// CHANNEL-MAJOR voxel record (32 halfs = 64 B), s[] = half index:
//   s[ 0.. 8] = f0..f8  (ch0), s[9]  = pad
//   s[10..18] = f9..f17 (ch1), s[19] = pad
//   s[20..28] = f18..f26(ch2), s[29] = pad
//   s[30]     = sigma (f27),   s[31] = pad
// ---------------------------------------------------------------------------
__global__ __launch_bounds__(256) void prep_kernel(
    const float* __restrict__ tree, __half* __restrict__ vox, int nvox,
    const float* __restrict__ origins, const float* __restrict__ dirs_in,
    float* __restrict__ ckpt, int nB, int nGeomB)
{
    if ((int)blockIdx.x < nGeomB) {
        // ---- geometry checkpoints (one thread per ray, no gathers) ----
        int i = blockIdx.x * 256 + threadIdx.x;
        if (i >= nB) return;
        RAY_SETUP(i);
        float ck[NSEG];
        float t = t0;
        ck[0] = t0;
#pragma unroll
        for (int k = 1; k < NSEG; ++k) {
            if (t < tmax) {
                for (int j = 0; j < SEG_STEPS; ++j) {
                    int fl;
                    t += march_step(t, ox, oy, oz, dx, dy, dz, idx, idy, idz, &fl);
                    if (t >= tmax) break;
                }
            }
            ck[k] = t;
        }
        float* cp = ckpt + (size_t)i * NSEG;
        *(float4*)(cp + 0) = make_float4(ck[0], ck[1], ck[2], ck[3]);
        *(float4*)(cp + 4) = make_float4(ck[4], ck[5], ck[6], ck[7]);
    } else {
        // ---- fp32 -> fp16 convert + channel-major reorder, 2 thr/voxel ----
        int tid2 = (blockIdx.x - nGeomB) * 256 + threadIdx.x;
        int v = tid2 >> 1;
        int q = tid2 & 1;
        if (v >= nvox) return;
        const float* src = tree + (size_t)v * DATA_DIM;
        uint4* d = (uint4*)(vox + (size_t)v * PAD_DIM) + q * 2;
        union Q { __half2 h[4]; uint4 u; } w;
        if (q == 0) {
            float4 L0 = *(const float4*)(src + 0);   // f0..f3
            float4 L1 = *(const float4*)(src + 4);   // f4..f7
            float4 L2 = *(const float4*)(src + 8);   // f8..f11
            float4 L3 = *(const float4*)(src + 12);  // f12..f15
            w.h[0] = __floats2half2_rn(L0.x, L0.y);  // f0 f1
            w.h[1] = __floats2half2_rn(L0.z, L0.w);  // f2 f3
            w.h[2] = __floats2half2_rn(L1.x, L1.y);  // f4 f5
            w.h[3] = __floats2half2_rn(L1.z, L1.w);  // f6 f7
            d[0] = w.u;
            w.h[0] = __floats2half2_rn(L2.x, 0.f);   // f8 pad
            w.h[1] = __floats2half2_rn(L2.y, L2.z);  // f9 f10
            w.h[2] = __floats2half2_rn(L2.w, L3.x);  // f11 f12
            w.h[3] = __floats2half2_rn(L3.y, L3.z);  // f13 f14
            d[1] = w.u;
        } else {
            float4 M0 = *(const float4*)(src + 12);  // f12..f15
            float4 M1 = *(const float4*)(src + 16);  // f16..f19
            float4 M2 = *(const float4*)(src + 20);  // f20..f23
            float4 M3 = *(const float4*)(src + 24);  // f24..f27
            w.h[0] = __floats2half2_rn(M0.w, M1.x);  // f15 f16
            w.h[1] = __floats2half2_rn(M1.y, 0.f);   // f17 pad
            w.h[2] = __floats2half2_rn(M1.z, M1.w);  // f18 f19
            w.h[3] = __floats2half2_rn(M2.x, M2.y);  // f20 f21
            d[0] = w.u;
            w.h[0] = __floats2half2_rn(M2.z, M2.w);  // f22 f23
            w.h[1] = __floats2half2_rn(M3.x, M3.y);  // f24 f25
            w.h[2] = __floats2half2_rn(M3.z, 0.f);   // f26 pad
            w.h[3] = __floats2half2_rn(M3.w, 0.f);   // sigma pad
            d[1] = w.u;
        }
    }
}

// ---------------------------------------------------------------------------
// Main march: 8 threads/ray, one per 32-step segment, 8-lane shuffle combine.
// NEW: register double-buffered gather prefetch. The t-chain is purely
// geometric (independent of loaded data), so step i+1's 64B record is
// issued BEFORE shading step i; the compiler then waits with a counted
// vmcnt (not 0), hiding L2/L3 gather latency under ~70 VALU ops + TLP.
// The one-past-end prefetch is always in-bounds (clamped index) and
// finite, so no guard is needed — each half-iteration is one basic block.
// ---------------------------------------------------------------------------
typedef union { uint4 u[4]; h2f h[16]; _Float16 s[32]; } Rec;

#define LOADREC(R, FLAT) do {                                                 \
    const uint4* _vp = (const uint4*)(vox_grid + (size_t)(FLAT) * PAD_DIM);   \
    (R).u[0] = _vp[0]; (R).u[1] = _vp[1];                                     \
    (R).u[2] = _vp[2]; (R).u[3] = _vp[3]; } while (0)

#define SHADE(R, DT) do {                                                     \
    float _sig = fmaxf((float)(R).s[30], 0.0f);                               \
    float _att = fexp2((DT) * _sig * nds);                                    \
    float _la  = light * _att;                                                \
    float _w   = light - _la;                                                 \
    light = _la;                                                              \
    float _r0 = fdot2((R).h[ 4], S8z, fdot2((R).h[ 3], S67, fdot2((R).h[ 2], S45, \
                fdot2((R).h[ 1], S23, fdot2((R).h[ 0], S01, 0.0f)))));        \
    float _r1 = fdot2((R).h[ 9], S8z, fdot2((R).h[ 8], S67, fdot2((R).h[ 7], S45, \
                fdot2((R).h[ 6], S23, fdot2((R).h[ 5], S01, 0.0f)))));        \
    float _r2 = fdot2((R).h[14], S8z, fdot2((R).h[13], S67, fdot2((R).h[12], S45, \
                fdot2((R).h[11], S23, fdot2((R).h[10], S01, 0.0f)))));        \
    float _g0 = frcp(1.0f + fexp2neg(_r0));                                   \
    float _g1 = frcp(1.0f + fexp2neg(_r1));                                   \
    float _g2 = frcp(1.0f + fexp2neg(_r2));                                   \
    o0 = fmaf(_w, _g0, o0);                                                   \
    o1 = fmaf(_w, _g1, o1);                                                   \
    o2 = fmaf(_w, _g2, o2); } while (0)

__global__ __launch_bounds__(256, 8) void march_kernel(
    const __half* __restrict__ vox_grid,
    const float* __restrict__ origins,
    const float* __restrict__ dirs_in,
    const float* __restrict__ viewdirs,
    const float* __restrict__ invradius,
    const float* __restrict__ ckpt,
    float* __restrict__ out, int nB)
{
    int tid = blockIdx.x * blockDim.x + threadIdx.x;
    int ray = tid >> 3;
    int seg = tid & 7;
    if (ray >= nB) return;

    RAY_SETUP(ray);

    float vx = viewdirs[3*ray+0], vy = viewdirs[3*ray+1], vz = viewdirs[3*ray+2];
    float irx = invradius[0], iry = invradius[1], irz = invradius[2];
    float qx = dx / irx, qy = dy / iry, qz = dz / irz;
    float delta_scale = sqrtf(qx*qx + qy*qy + qz*qz);

    const float C1 = 0.4886025119029199f;
    const float L2E = 1.4426950408889634f;   // log2(e), folded into SH + att
    float sh0 = 0.28209479177387814f;
    float sh1 = -C1 * vy;
    float sh2 =  C1 * vz;
    float sh3 = -C1 * vx;
    float sh4 =  1.0925484305920792f  * vx * vy;
    float sh5 = -1.0925484305920792f * vy * vz;
    float sh6 =  0.31539156525252005f * (2.0f*vz*vz - vx*vx - vy*vy);
    float sh7 = -1.0925484305920792f * vx * vz;
    float sh8 =  0.5462742152960396f  * (vx*vx - vy*vy);

    // loop-invariant fp16 coefficient pairs (pre-scaled by log2 e)
    h2f S01 = { (_Float16)(sh0*L2E), (_Float16)(sh1*L2E) };
    h2f S23 = { (_Float16)(sh2*L2E), (_Float16)(sh3*L2E) };
    h2f S45 = { (_Float16)(sh4*L2E), (_Float16)(sh5*L2E) };
    h2f S67 = { (_Float16)(sh6*L2E), (_Float16)(sh7*L2E) };
    h2f S8z = { (_Float16)(sh8*L2E), (_Float16)0.0f      };
    float nds = -delta_scale * L2E;          // att = 2^(dt*sigma*nds)

    float t = ckpt[(size_t)ray * NSEG + seg];
    float light = 1.0f;                      // segment-local transmittance
    float o0 = 0.f, o1 = 0.f, o2 = 0.f;

    if (t < tmax) {
        int fA, fB;
        Rec A, B;
        float dtA = march_step(t, ox, oy, oz, dx, dy, dz, idx, idy, idz, &fA);
        LOADREC(A, fA);
        int i = 0;
        for (;;) {
            // prefetch step i+1 (possibly one past end — harmless, in-bounds)
            t += dtA;
            float dtB = march_step(t, ox, oy, oz, dx, dy, dz, idx, idy, idz, &fB);
            LOADREC(B, fB);
            SHADE(A, dtA);
            if (++i >= SEG_STEPS || t >= tmax) break;

            t += dtB;
            dtA = march_step(t, ox, oy, oz, dx, dy, dz, idx, idy, idz, &fA);
            LOADREC(A, fA);
            SHADE(B, dtB);
            if (++i >= SEG_STEPS || t >= tmax) break;
        }
    }

    // ---- 8-lane combine (lanes 8m..8m+7 hold segments 0..7 of one ray) ----
    float l0 = __shfl(light, 0, 8);
    float l1 = __shfl(light, 1, 8);
    float l2 = __shfl(light, 2, 8);
    float l3 = __shfl(light, 3, 8);
    float l4 = __shfl(light, 4, 8);
    float l5 = __shfl(light, 5, 8);
    float l6 = __shfl(light, 6, 8);
    float l7 = __shfl(light, 7, 8);

    float P = 1.0f;
    if (seg > 0) P *= l0;
    if (seg > 1) P *= l1;
    if (seg > 2) P *= l2;
    if (seg > 3) P *= l3;
    if (seg > 4) P *= l4;
    if (seg > 5) P *= l5;
    if (seg > 6) P *= l6;
    float total_light = l0*l1*l2*l3*l4*l5*l6*l7;

    o0 *= P; o1 *= P; o2 *= P;
    o0 += __shfl_xor(o0, 1, 8); o0 += __shfl_xor(o0, 2, 8); o0 += __shfl_xor(o0, 4, 8);
    o1 += __shfl_xor(o1, 1, 8); o1 += __shfl_xor(o1, 2, 8); o1 += __shfl_xor(o1, 4, 8);
    o2 += __shfl_xor(o2, 1, 8); o2 += __shfl_xor(o2, 2, 8); o2 += __shfl_xor(o2, 4, 8);

    if (seg == 0) {
        out[3*ray+0] = o0 + total_light * BG;
        out[3*ray+1] = o1 + total_light * BG;
        out[3*ray+2] = o2 + total_light * BG;
    }
}

extern "C" void kernel_launch(void* const* d_in, const int* in_sizes, int n_in,
                              void* d_out, int out_size, void* d_ws, size_t ws_size,
                              hipStream_t stream) {
    const float* tree      = (const float*)d_in[0];
    const float* origins   = (const float*)d_in[1];
    const float* dirs      = (const float*)d_in[2];
    const float* viewdirs  = (const float*)d_in[3];
    const float* invradius = (const float*)d_in[4];
    float* out = (float*)d_out;

    int nB   = in_sizes[1] / 3;
    int nvox = in_sizes[0] / DATA_DIM;

    const int block = 256;
    __half* hgrid = (__half*)d_ws;
    float* ckpt = (float*)((char*)d_ws + (size_t)nvox * PAD_DIM * sizeof(__half));

    int nGeomB = (nB + block - 1) / block;
    int nConvB = (nvox * 2 + block - 1) / block;
    prep_kernel<<<nGeomB + nConvB, block, 0, stream>>>(
        tree, hgrid, nvox, origins, dirs, ckpt, nB, nGeomB);

    int nmarch = nB * NSEG;
    march_kernel<<<(nmarch + block - 1) / block, block, 0, stream>>>(
        hgrid, origins, dirs, viewdirs, invradius, ckpt, out, nB);
    (void)ws_size;
}

// Round 4
// 698.430 us; speedup vs baseline: 1.0114x; 1.0114x over previous
//
#include <hip/hip_runtime.h>
#include <hip/hip_fp16.h>
#include <math.h>

#define GRID_R 128
#define DATA_DIM 28
#define PAD_DIM 32
#define NSEG 8
#define SEG_STEPS 32
#define STEP_SIZE 0.001f
#define BG 1.0f

// packed half2 for v_dot2
typedef _Float16 h2f __attribute__((ext_vector_type(2)));
typedef unsigned int u32x4 __attribute__((ext_vector_type(4)));

// D = a.x*b.x + a.y*b.y + c (f16 products, f32 accumulate) — one VOP3P instr.
#if __has_builtin(__builtin_amdgcn_fdot2)
__device__ __forceinline__ float fdot2(h2f a, h2f b, float c) {
    return __builtin_amdgcn_fdot2(a, b, c, false);
}
#else
__device__ __forceinline__ float fdot2(h2f a, h2f b, float c) {
    return fmaf((float)a.x, (float)b.x, fmaf((float)a.y, (float)b.y, c));
}
#endif

#if __has_builtin(__builtin_amdgcn_exp2f)
__device__ __forceinline__ float fexp2(float x)    { return __builtin_amdgcn_exp2f(x); }
__device__ __forceinline__ float fexp2neg(float x) { return __builtin_amdgcn_exp2f(-x); }
#else
__device__ __forceinline__ float fexp2(float x) {
    float r; asm("v_exp_f32 %0, %1" : "=v"(r) : "v"(x)); return r;
}
__device__ __forceinline__ float fexp2neg(float x) {
    float r; asm("v_exp_f32 %0, -%1" : "=v"(r) : "v"(x)); return r;
}
#endif

#if __has_builtin(__builtin_amdgcn_rcpf)
__device__ __forceinline__ float frcp(float x) { return __builtin_amdgcn_rcpf(x); }
#else
__device__ __forceinline__ float frcp(float x) {
    float r; asm("v_rcp_f32 %0, %1" : "=v"(r) : "v"(x)); return r;
}
#endif

// reinterpret one u32 as a packed half2
__device__ __forceinline__ h2f bch(unsigned int v) {
    union { unsigned int u; h2f h; } x; x.u = v; return x.h;
}

// ---------------------------------------------------------------------------
// Shared per-step geometry — bit-identical to the verified kernel (voxel
// picks at cell boundaries are rounding-sensitive). Safe for ANY finite t
// (clamped index, finite dt) — that makes unguarded prefetch legal.
// ---------------------------------------------------------------------------
__device__ __forceinline__ float march_step(
    float t, float ox, float oy, float oz,
    float dx, float dy, float dz,
    float idx, float idy, float idz, int* flat)
{
    float px = (ox + t*dx) * 128.0f;
    float py = (oy + t*dy) * 128.0f;
    float pz = (oz + t*dz) * 128.0f;
    float fx = fminf(fmaxf(floorf(px), 0.0f), 127.0f);
    float fy = fminf(fmaxf(floorf(py), 0.0f), 127.0f);
    float fz = fminf(fmaxf(floorf(pz), 0.0f), 127.0f);
    float ff = fmaf(fx, 16384.0f, fmaf(fy, 128.0f, fz));   // exact, < 2^21
    *flat = (int)ff;
    float cx = px - fx, cy = py - fy, cz = pz - fz;
    float a1x = -cx*idx, a1y = -cy*idy, a1z = -cz*idz;
    float a2x = a1x+idx, a2y = a1y+idy, a2z = a1z+idz;
    float e1 = fminf(fminf(fmaxf(a1x,a2x), fmaxf(a1y,a2y)), fmaxf(a1z,a2z));
    e1 = fminf(e1, 1e9f);
    return e1 * (1.0f/128.0f) + STEP_SIZE;
}

// common ray setup (unchanged)
#define RAY_SETUP(i)                                                          \
    float ox = origins[3*(i)+0], oy = origins[3*(i)+1], oz = origins[3*(i)+2];\
    float dx = dirs_in[3*(i)+0], dy = dirs_in[3*(i)+1], dz = dirs_in[3*(i)+2];\
    float dn = sqrtf(dx*dx + dy*dy + dz*dz);                                  \
    float rdn = 1.0f / dn;                                                    \
    dx *= rdn; dy *= rdn; dz *= rdn;                                          \
    float idx = 1.0f / (dx + 1e-9f);                                          \
    float idy = 1.0f / (dy + 1e-9f);                                          \
    float idz = 1.0f / (dz + 1e-9f);                                          \
    float t1x = -ox*idx, t1y = -oy*idy, t1z = -oz*idz;                        \
    float t2x = t1x+idx, t2y = t1y+idy, t2z = t1z+idz;                        \
    float t0   = fmaxf(fmaxf(fmaxf(fminf(t1x,t2x), fminf(t1y,t2y)), fminf(t1z,t2z)), 0.0f); \
    float tmax = fminf(fminf(fminf(fmaxf(t1x,t2x), fmaxf(t1y,t2y)), fmaxf(t1z,t2z)), 1e9f);

// ---------------------------------------------------------------------------
// Fused pre-pass: geom (blocks [0, nGeomB)) + fp32->fp16 grid convert
// (remaining blocks, 2 threads/voxel). Unchanged from the verified round-2
// kernel.
//
// CHANNEL-MAJOR voxel record (32 halfs = 64 B), s[] = half index:
//   s[ 0.. 8] = f0..f8  (ch0), s[9]  = pad
//   s[10..18] = f9..f17 (ch1), s[19] = pad
//   s[20..28] = f18..f26(ch2), s[29] = pad
//   s[30]     = sigma (f27),   s[31] = pad
// ---------------------------------------------------------------------------
__global__ __launch_bounds__(256) void prep_kernel(
    const float* __restrict__ tree, __half* __restrict__ vox, int nvox,
    const float* __restrict__ origins, const float* __restrict__ dirs_in,
    float* __restrict__ ckpt, int nB, int nGeomB)
{
    if ((int)blockIdx.x < nGeomB) {
        int i = blockIdx.x * 256 + threadIdx.x;
        if (i >= nB) return;
        RAY_SETUP(i);
        float ck[NSEG];
        float t = t0;
        ck[0] = t0;
#pragma unroll
        for (int k = 1; k < NSEG; ++k) {
            if (t < tmax) {
                for (int j = 0; j < SEG_STEPS; ++j) {
                    int fl;
                    t += march_step(t, ox, oy, oz, dx, dy, dz, idx, idy, idz, &fl);
                    if (t >= tmax) break;
                }
            }
            ck[k] = t;
        }
        float* cp = ckpt + (size_t)i * NSEG;
        *(float4*)(cp + 0) = make_float4(ck[0], ck[1], ck[2], ck[3]);
        *(float4*)(cp + 4) = make_float4(ck[4], ck[5], ck[6], ck[7]);
    } else {
        int tid2 = (blockIdx.x - nGeomB) * 256 + threadIdx.x;
        int v = tid2 >> 1;
        int q = tid2 & 1;
        if (v >= nvox) return;
        const float* src = tree + (size_t)v * DATA_DIM;
        uint4* d = (uint4*)(vox + (size_t)v * PAD_DIM) + q * 2;
        union Q { __half2 h[4]; uint4 u; } w;
        if (q == 0) {
            float4 L0 = *(const float4*)(src + 0);   // f0..f3
            float4 L1 = *(const float4*)(src + 4);   // f4..f7
            float4 L2 = *(const float4*)(src + 8);   // f8..f11
            float4 L3 = *(const float4*)(src + 12);  // f12..f15
            w.h[0] = __floats2half2_rn(L0.x, L0.y);  // f0 f1
            w.h[1] = __floats2half2_rn(L0.z, L0.w);  // f2 f3
            w.h[2] = __floats2half2_rn(L1.x, L1.y);  // f4 f5
            w.h[3] = __floats2half2_rn(L1.z, L1.w);  // f6 f7
            d[0] = w.u;
            w.h[0] = __floats2half2_rn(L2.x, 0.f);   // f8 pad
            w.h[1] = __floats2half2_rn(L2.y, L2.z);  // f9 f10
            w.h[2] = __floats2half2_rn(L2.w, L3.x);  // f11 f12
            w.h[3] = __floats2half2_rn(L3.y, L3.z);  // f13 f14
            d[1] = w.u;
        } else {
            float4 M0 = *(const float4*)(src + 12);  // f12..f15
            float4 M1 = *(const float4*)(src + 16);  // f16..f19
            float4 M2 = *(const float4*)(src + 20);  // f20..f23
            float4 M3 = *(const float4*)(src + 24);  // f24..f27
            w.h[0] = __floats2half2_rn(M0.w, M1.x);  // f15 f16
            w.h[1] = __floats2half2_rn(M1.y, 0.f);   // f17 pad
            w.h[2] = __floats2half2_rn(M1.z, M1.w);  // f18 f19
            w.h[3] = __floats2half2_rn(M2.x, M2.y);  // f20 f21
            d[0] = w.u;
            w.h[0] = __floats2half2_rn(M2.z, M2.w);  // f22 f23
            w.h[1] = __floats2half2_rn(M3.x, M3.y);  // f24 f25
            w.h[2] = __floats2half2_rn(M3.z, 0.f);   // f26 pad
            w.h[3] = __floats2half2_rn(M3.w, 0.f);   // sigma pad
            d[1] = w.u;
        }
    }
}

// ---------------------------------------------------------------------------
// Main march. Round-3 lesson: the compiler COLLAPSES source-level register
// double-buffering (VGPR stayed 28 -> second buffer never lived). This
// version pins the pipeline with inline asm:
//   - 4x global_load_dwordx4 per record issued via asm volatile (cannot be
//     sunk below the shade);
//   - counted "s_waitcnt vmcnt(4)" before shading (keeps the next record's
//     4 loads in flight across the shade — the AITER/T4 pattern);
//   - sched_barrier(0) after each waitcnt (rule #18: hipcc hoists
//     register-only consumers past asm waitcnt otherwise);
//   - one vmcnt(0) drain at loop exit so in-flight loads can't clobber
//     reallocated VGPRs.
// WAR on the refill is safe: in-order issue means shade VALU reads complete
// at issue, before the refill load issues; dests are written only at return.
// launch_bounds(256,6): VGPR cap 84 so both buffers (8x uint4) genuinely fit.
// ---------------------------------------------------------------------------
#define LOADREC(A0,A1,A2,A3, FLAT) do {                                       \
    unsigned long long _ad =                                                  \
        (unsigned long long)(vox_grid + (size_t)(FLAT) * PAD_DIM);            \
    asm volatile("global_load_dwordx4 %0, %[ad], off\n\t"                     \
                 "global_load_dwordx4 %1, %[ad], off offset:16\n\t"           \
                 "global_load_dwordx4 %2, %[ad], off offset:32\n\t"           \
                 "global_load_dwordx4 %3, %[ad], off offset:48"               \
                 : "=&v"(A0), "=&v"(A1), "=&v"(A2), "=&v"(A3)                 \
                 : [ad] "v"(_ad)); } while (0)

#define WAIT4()  do { asm volatile("s_waitcnt vmcnt(4)" ::: "memory");        \
                      __builtin_amdgcn_sched_barrier(0); } while (0)
#define DRAIN()  do { asm volatile("s_waitcnt vmcnt(0)" ::: "memory");        \
                      __builtin_amdgcn_sched_barrier(0); } while (0)

// record halves: A0=h[0..3], A1=h[4..7], A2=h[8..11], A3=h[12..15]
#define SHADE(A0,A1,A2,A3, DT) do {                                           \
    float _sig = fmaxf((float)bch((A3)[3]).x, 0.0f);                          \
    float _att = fexp2((DT) * _sig * nds);                                    \
    float _la  = light * _att;                                                \
    float _w   = light - _la;                                                 \
    light = _la;                                                              \
    float _r0 = fdot2(bch((A1)[0]), S8z, fdot2(bch((A0)[3]), S67,             \
                fdot2(bch((A0)[2]), S45, fdot2(bch((A0)[1]), S23,             \
                fdot2(bch((A0)[0]), S01, 0.0f)))));                           \
    float _r1 = fdot2(bch((A2)[1]), S8z, fdot2(bch((A2)[0]), S67,             \
                fdot2(bch((A1)[3]), S45, fdot2(bch((A1)[2]), S23,             \
                fdot2(bch((A1)[1]), S01, 0.0f)))));                           \
    float _r2 = fdot2(bch((A3)[2]), S8z, fdot2(bch((A3)[1]), S67,             \
                fdot2(bch((A3)[0]), S45, fdot2(bch((A2)[3]), S23,             \
                fdot2(bch((A2)[2]), S01, 0.0f)))));                           \
    float _g0 = frcp(1.0f + fexp2neg(_r0));                                   \
    float _g1 = frcp(1.0f + fexp2neg(_r1));                                   \
    float _g2 = frcp(1.0f + fexp2neg(_r2));                                   \
    o0 = fmaf(_w, _g0, o0);                                                   \
    o1 = fmaf(_w, _g1, o1);                                                   \
    o2 = fmaf(_w, _g2, o2); } while (0)

__global__ __launch_bounds__(256, 6) void march_kernel(
    const __half* __restrict__ vox_grid,
    const float* __restrict__ origins,
    const float* __restrict__ dirs_in,
    const float* __restrict__ viewdirs,
    const float* __restrict__ invradius,
    const float* __restrict__ ckpt,
    float* __restrict__ out, int nB)
{
    int tid = blockIdx.x * blockDim.x + threadIdx.x;
    int ray = tid >> 3;
    int seg = tid & 7;
    if (ray >= nB) return;

    RAY_SETUP(ray);

    float vx = viewdirs[3*ray+0], vy = viewdirs[3*ray+1], vz = viewdirs[3*ray+2];
    float irx = invradius[0], iry = invradius[1], irz = invradius[2];
    float qx = dx / irx, qy = dy / iry, qz = dz / irz;
    float delta_scale = sqrtf(qx*qx + qy*qy + qz*qz);

    const float C1 = 0.4886025119029199f;
    const float L2E = 1.4426950408889634f;   // log2(e), folded into SH + att
    float sh0 = 0.28209479177387814f;
    float sh1 = -C1 * vy;
    float sh2 =  C1 * vz;
    float sh3 = -C1 * vx;
    float sh4 =  1.0925484305920792f  * vx * vy;
    float sh5 = -1.0925484305920792f * vy * vz;
    float sh6 =  0.31539156525252005f * (2.0f*vz*vz - vx*vx - vy*vy);
    float sh7 = -1.0925484305920792f * vx * vz;
    float sh8 =  0.5462742152960396f  * (vx*vx - vy*vy);

    // loop-invariant fp16 coefficient pairs (pre-scaled by log2 e)
    h2f S01 = { (_Float16)(sh0*L2E), (_Float16)(sh1*L2E) };
    h2f S23 = { (_Float16)(sh2*L2E), (_Float16)(sh3*L2E) };
    h2f S45 = { (_Float16)(sh4*L2E), (_Float16)(sh5*L2E) };
    h2f S67 = { (_Float16)(sh6*L2E), (_Float16)(sh7*L2E) };
    h2f S8z = { (_Float16)(sh8*L2E), (_Float16)0.0f      };
    float nds = -delta_scale * L2E;          // att = 2^(dt*sigma*nds)

    float t = ckpt[(size_t)ray * NSEG + seg];
    float light = 1.0f;                      // segment-local transmittance
    float o0 = 0.f, o1 = 0.f, o2 = 0.f;

    if (t < tmax) {
        u32x4 a0, a1, a2, a3, b0, b1, b2, b3;
        int fA, fB;
        float dtA = march_step(t, ox, oy, oz, dx, dy, dz, idx, idy, idz, &fA);
        LOADREC(a0, a1, a2, a3, fA);
        int i = 0;
        for (;;) {
            // prefetch step i+1 (possibly one past end — in-bounds, finite)
            t += dtA;
            float dtB = march_step(t, ox, oy, oz, dx, dy, dz, idx, idy, idz, &fB);
            LOADREC(b0, b1, b2, b3, fB);
            WAIT4();                       // A complete, B still in flight
            SHADE(a0, a1, a2, a3, dtA);
            if (++i >= SEG_STEPS || t >= tmax) break;

            t += dtB;
            dtA = march_step(t, ox, oy, oz, dx, dy, dz, idx, idy, idz, &fA);
            LOADREC(a0, a1, a2, a3, fA);
            WAIT4();                       // B complete, A' still in flight
            SHADE(b0, b1, b2, b3, dtB);
            if (++i >= SEG_STEPS || t >= tmax) break;
        }
        DRAIN();   // in-flight prefetch must not clobber reallocated regs
    }

    // ---- 8-lane combine (lanes 8m..8m+7 hold segments 0..7 of one ray) ----
    float l0 = __shfl(light, 0, 8);
    float l1 = __shfl(light, 1, 8);
    float l2 = __shfl(light, 2, 8);
    float l3 = __shfl(light, 3, 8);
    float l4 = __shfl(light, 4, 8);
    float l5 = __shfl(light, 5, 8);
    float l6 = __shfl(light, 6, 8);
    float l7 = __shfl(light, 7, 8);

    float P = 1.0f;
    if (seg > 0) P *= l0;
    if (seg > 1) P *= l1;
    if (seg > 2) P *= l2;
    if (seg > 3) P *= l3;
    if (seg > 4) P *= l4;
    if (seg > 5) P *= l5;
    if (seg > 6) P *= l6;
    float total_light = l0*l1*l2*l3*l4*l5*l6*l7;

    o0 *= P; o1 *= P; o2 *= P;
    o0 += __shfl_xor(o0, 1, 8); o0 += __shfl_xor(o0, 2, 8); o0 += __shfl_xor(o0, 4, 8);
    o1 += __shfl_xor(o1, 1, 8); o1 += __shfl_xor(o1, 2, 8); o1 += __shfl_xor(o1, 4, 8);
    o2 += __shfl_xor(o2, 1, 8); o2 += __shfl_xor(o2, 2, 8); o2 += __shfl_xor(o2, 4, 8);

    if (seg == 0) {
        out[3*ray+0] = o0 + total_light * BG;
        out[3*ray+1] = o1 + total_light * BG;
        out[3*ray+2] = o2 + total_light * BG;
    }
}

extern "C" void kernel_launch(void* const* d_in, const int* in_sizes, int n_in,
                              void* d_out, int out_size, void* d_ws, size_t ws_size,
                              hipStream_t stream) {
    const float* tree      = (const float*)d_in[0];
    const float* origins   = (const float*)d_in[1];
    const float* dirs      = (const float*)d_in[2];
    const float* viewdirs  = (const float*)d_in[3];
    const float* invradius = (const float*)d_in[4];
    float* out = (float*)d_out;

    int nB   = in_sizes[1] / 3;
    int nvox = in_sizes[0] / DATA_DIM;

    const int block = 256;
    __half* hgrid = (__half*)d_ws;
    float* ckpt = (float*)((char*)d_ws + (size_t)nvox * PAD_DIM * sizeof(__half));

    int nGeomB = (nB + block - 1) / block;
    int nConvB = (nvox * 2 + block - 1) / block;
    prep_kernel<<<nGeomB + nConvB, block, 0, stream>>>(
        tree, hgrid, nvox, origins, dirs, ckpt, nB, nGeomB);

    int nmarch = nB * NSEG;
    march_kernel<<<(nmarch + block - 1) / block, block, 0, stream>>>(
        hgrid, origins, dirs, viewdirs, invradius, ckpt, out, nB);
    (void)ws_size;
}

// Round 5
// 641.463 us; speedup vs baseline: 1.1012x; 1.0888x over previous
//
#include <hip/hip_runtime.h>
#include <hip/hip_fp16.h>
#include <math.h>

#define GRID_R 128
#define DATA_DIM 28
#define PAD_DIM 32
#define NSEG 8
#define SEG_STEPS 32
#define STEP_SIZE 0.001f
#define BG 1.0f

// packed half2 for v_dot2
typedef _Float16 h2f __attribute__((ext_vector_type(2)));

// D = a.x*b.x + a.y*b.y + c (f16 products, f32 accumulate) — one VOP3P instr.
#if __has_builtin(__builtin_amdgcn_fdot2)
__device__ __forceinline__ float fdot2(h2f a, h2f b, float c) {
    return __builtin_amdgcn_fdot2(a, b, c, false);
}
#else
__device__ __forceinline__ float fdot2(h2f a, h2f b, float c) {
    return fmaf((float)a.x, (float)b.x, fmaf((float)a.y, (float)b.y, c));
}
#endif

#if __has_builtin(__builtin_amdgcn_exp2f)
__device__ __forceinline__ float fexp2(float x)    { return __builtin_amdgcn_exp2f(x); }
__device__ __forceinline__ float fexp2neg(float x) { return __builtin_amdgcn_exp2f(-x); }
#else
__device__ __forceinline__ float fexp2(float x) {
    float r; asm("v_exp_f32 %0, %1" : "=v"(r) : "v"(x)); return r;
}
__device__ __forceinline__ float fexp2neg(float x) {
    float r; asm("v_exp_f32 %0, -%1" : "=v"(r) : "v"(x)); return r;
}
#endif

#if __has_builtin(__builtin_amdgcn_rcpf)
__device__ __forceinline__ float frcp(float x) { return __builtin_amdgcn_rcpf(x); }
#else
__device__ __forceinline__ float frcp(float x) {
    float r; asm("v_rcp_f32 %0, %1" : "=v"(r) : "v"(x)); return r;
}
#endif

// ---------------------------------------------------------------------------
// Shared per-step geometry — bit-identical to the verified kernel (voxel
// picks at cell boundaries are rounding-sensitive).
// ---------------------------------------------------------------------------
__device__ __forceinline__ float march_step(
    float t, float ox, float oy, float oz,
    float dx, float dy, float dz,
    float idx, float idy, float idz, int* flat)
{
    float px = (ox + t*dx) * 128.0f;
    float py = (oy + t*dy) * 128.0f;
    float pz = (oz + t*dz) * 128.0f;
    float fx = fminf(fmaxf(floorf(px), 0.0f), 127.0f);
    float fy = fminf(fmaxf(floorf(py), 0.0f), 127.0f);
    float fz = fminf(fmaxf(floorf(pz), 0.0f), 127.0f);
    float ff = fmaf(fx, 16384.0f, fmaf(fy, 128.0f, fz));   // exact, < 2^21
    *flat = (int)ff;
    float cx = px - fx, cy = py - fy, cz = pz - fz;
    float a1x = -cx*idx, a1y = -cy*idy, a1z = -cz*idz;
    float a2x = a1x+idx, a2y = a1y+idy, a2z = a1z+idz;
    float e1 = fminf(fminf(fmaxf(a1x,a2x), fmaxf(a1y,a2y)), fmaxf(a1z,a2z));
    e1 = fminf(e1, 1e9f);
    return e1 * (1.0f/128.0f) + STEP_SIZE;
}

// common ray setup (unchanged)
#define RAY_SETUP(i)                                                          \
    float ox = origins[3*(i)+0], oy = origins[3*(i)+1], oz = origins[3*(i)+2];\
    float dx = dirs_in[3*(i)+0], dy = dirs_in[3*(i)+1], dz = dirs_in[3*(i)+2];\
    float dn = sqrtf(dx*dx + dy*dy + dz*dz);                                  \
    float rdn = 1.0f / dn;                                                    \
    dx *= rdn; dy *= rdn; dz *= rdn;                                          \
    float idx = 1.0f / (dx + 1e-9f);                                          \
    float idy = 1.0f / (dy + 1e-9f);                                          \
    float idz = 1.0f / (dz + 1e-9f);                                          \
    float t1x = -ox*idx, t1y = -oy*idy, t1z = -oz*idz;                        \
    float t2x = t1x+idx, t2y = t1y+idy, t2z = t1z+idz;                        \
    float t0   = fmaxf(fmaxf(fmaxf(fminf(t1x,t2x), fminf(t1y,t2y)), fminf(t1z,t2z)), 0.0f); \
    float tmax = fminf(fminf(fminf(fmaxf(t1x,t2x), fmaxf(t1y,t2y)), fmaxf(t1z,t2z)), 1e9f);

// ---------------------------------------------------------------------------
// Fused pre-pass, three block ranges:
//   [0, nGeomB)                    : per-ray geometry checkpoints
//   [nGeomB, nGeomB+nConvB)        : fp32 -> fp16 convert (2 thr/voxel)
//   [nGeomB+nConvB, +nMaskB)       : occupancy bitmask (1 bit/voxel, 262 KB)
// Mask bit v = (tree[v*28+27] > 0). sigma<=0  =>  relu=0 => att=1 => weight=0
// exactly, so march can skip the 64B record fetch bit-exactly. The mask is
// L2-resident (262 KB/XCD) -> probing it costs ~no fabric traffic.
//
// CHANNEL-MAJOR voxel record (32 halfs = 64 B), s[] = half index:
//   s[ 0.. 8] = f0..f8  (ch0), s[9]  = pad
//   s[10..18] = f9..f17 (ch1), s[19] = pad
//   s[20..28] = f18..f26(ch2), s[29] = pad
//   s[30]     = sigma (f27),   s[31] = pad
// ---------------------------------------------------------------------------
__global__ __launch_bounds__(256) void prep_kernel(
    const float* __restrict__ tree, __half* __restrict__ vox, int nvox,
    const float* __restrict__ origins, const float* __restrict__ dirs_in,
    float* __restrict__ ckpt, unsigned char* __restrict__ occ_mask,
    int nB, int nGeomB, int nConvB)
{
    int bid = (int)blockIdx.x;
    if (bid < nGeomB) {
        // ---- geometry checkpoints (one thread per ray, no gathers) ----
        int i = bid * 256 + threadIdx.x;
        if (i >= nB) return;
        RAY_SETUP(i);
        float ck[NSEG];
        float t = t0;
        ck[0] = t0;
#pragma unroll
        for (int k = 1; k < NSEG; ++k) {
            if (t < tmax) {
                for (int j = 0; j < SEG_STEPS; ++j) {
                    int fl;
                    t += march_step(t, ox, oy, oz, dx, dy, dz, idx, idy, idz, &fl);
                    if (t >= tmax) break;
                }
            }
            ck[k] = t;
        }
        float* cp = ckpt + (size_t)i * NSEG;
        *(float4*)(cp + 0) = make_float4(ck[0], ck[1], ck[2], ck[3]);
        *(float4*)(cp + 4) = make_float4(ck[4], ck[5], ck[6], ck[7]);
    } else if (bid < nGeomB + nConvB) {
        // ---- fp32 -> fp16 convert + channel-major reorder, 2 thr/voxel ----
        int tid2 = (bid - nGeomB) * 256 + threadIdx.x;
        int v = tid2 >> 1;
        int q = tid2 & 1;
        if (v >= nvox) return;
        const float* src = tree + (size_t)v * DATA_DIM;
        uint4* d = (uint4*)(vox + (size_t)v * PAD_DIM) + q * 2;
        union Q { __half2 h[4]; uint4 u; } w;
        if (q == 0) {
            float4 L0 = *(const float4*)(src + 0);   // f0..f3
            float4 L1 = *(const float4*)(src + 4);   // f4..f7
            float4 L2 = *(const float4*)(src + 8);   // f8..f11
            float4 L3 = *(const float4*)(src + 12);  // f12..f15
            w.h[0] = __floats2half2_rn(L0.x, L0.y);  // f0 f1
            w.h[1] = __floats2half2_rn(L0.z, L0.w);  // f2 f3
            w.h[2] = __floats2half2_rn(L1.x, L1.y);  // f4 f5
            w.h[3] = __floats2half2_rn(L1.z, L1.w);  // f6 f7
            d[0] = w.u;
            w.h[0] = __floats2half2_rn(L2.x, 0.f);   // f8 pad
            w.h[1] = __floats2half2_rn(L2.y, L2.z);  // f9 f10
            w.h[2] = __floats2half2_rn(L2.w, L3.x);  // f11 f12
            w.h[3] = __floats2half2_rn(L3.y, L3.z);  // f13 f14
            d[1] = w.u;
        } else {
            float4 M0 = *(const float4*)(src + 12);  // f12..f15
            float4 M1 = *(const float4*)(src + 16);  // f16..f19
            float4 M2 = *(const float4*)(src + 20);  // f20..f23
            float4 M3 = *(const float4*)(src + 24);  // f24..f27
            w.h[0] = __floats2half2_rn(M0.w, M1.x);  // f15 f16
            w.h[1] = __floats2half2_rn(M1.y, 0.f);   // f17 pad
            w.h[2] = __floats2half2_rn(M1.z, M1.w);  // f18 f19
            w.h[3] = __floats2half2_rn(M2.x, M2.y);  // f20 f21
            d[0] = w.u;
            w.h[0] = __floats2half2_rn(M2.z, M2.w);  // f22 f23
            w.h[1] = __floats2half2_rn(M3.x, M3.y);  // f24 f25
            w.h[2] = __floats2half2_rn(M3.z, 0.f);   // f26 pad
            w.h[3] = __floats2half2_rn(M3.w, 0.f);   // sigma pad
            d[1] = w.u;
        }
    } else {
        // ---- occupancy bitmask: 1 thread per 8 consecutive voxels ----
        int m = (bid - nGeomB - nConvB) * 256 + threadIdx.x;
        int nm = nvox >> 3;
        if (m >= nm) return;
        const float* s = tree + (size_t)m * 8 * DATA_DIM + (DATA_DIM - 1);
        unsigned int b = 0;
#pragma unroll
        for (int j = 0; j < 8; ++j)
            if (s[(size_t)j * DATA_DIM] > 0.0f) b |= (1u << j);
        occ_mask[m] = (unsigned char)b;
    }
}

// ---------------------------------------------------------------------------
// Main march: 8 threads/ray, one per 32-step segment, 8-lane shuffle combine.
// Rounds 2-4 established the memory path is THROUGHPUT-saturated at
// ~3.4 TB/s / ~54G lines/s for this random-gather pattern (depth-1 no-
// prefetch == depth-2 pinned-asm pipeline, both 43% VALUBusy) — so the only
// lever is FEWER LINE FETCHES. ~50% of voxels have sigma<=0 (relu kills
// them; att=exp(0)=1, weight=0 exactly), so we probe a 262 KB L2-resident
// occupancy bitmask per step and fetch+shade the 64 B record only for
// occupied voxels. Skip is bit-exact. Simple round-2 load structure
// (pipeline proven neutral).
// ---------------------------------------------------------------------------
typedef union { uint4 u[4]; h2f h[16]; _Float16 s[32]; } Rec;

__global__ __launch_bounds__(256, 8) void march_kernel(
    const __half* __restrict__ vox_grid,
    const unsigned char* __restrict__ occ_mask,
    const float* __restrict__ origins,
    const float* __restrict__ dirs_in,
    const float* __restrict__ viewdirs,
    const float* __restrict__ invradius,
    const float* __restrict__ ckpt,
    float* __restrict__ out, int nB)
{
    int tid = blockIdx.x * blockDim.x + threadIdx.x;
    int ray = tid >> 3;
    int seg = tid & 7;
    if (ray >= nB) return;

    RAY_SETUP(ray);

    float vx = viewdirs[3*ray+0], vy = viewdirs[3*ray+1], vz = viewdirs[3*ray+2];
    float irx = invradius[0], iry = invradius[1], irz = invradius[2];
    float qx = dx / irx, qy = dy / iry, qz = dz / irz;
    float delta_scale = sqrtf(qx*qx + qy*qy + qz*qz);

    const float C1 = 0.4886025119029199f;
    const float L2E = 1.4426950408889634f;   // log2(e), folded into SH + att
    float sh0 = 0.28209479177387814f;
    float sh1 = -C1 * vy;
    float sh2 =  C1 * vz;
    float sh3 = -C1 * vx;
    float sh4 =  1.0925484305920792f  * vx * vy;
    float sh5 = -1.0925484305920792f * vy * vz;
    float sh6 =  0.31539156525252005f * (2.0f*vz*vz - vx*vx - vy*vy);
    float sh7 = -1.0925484305920792f * vx * vz;
    float sh8 =  0.5462742152960396f  * (vx*vx - vy*vy);

    // loop-invariant fp16 coefficient pairs (pre-scaled by log2 e)
    h2f S01 = { (_Float16)(sh0*L2E), (_Float16)(sh1*L2E) };
    h2f S23 = { (_Float16)(sh2*L2E), (_Float16)(sh3*L2E) };
    h2f S45 = { (_Float16)(sh4*L2E), (_Float16)(sh5*L2E) };
    h2f S67 = { (_Float16)(sh6*L2E), (_Float16)(sh7*L2E) };
    h2f S8z = { (_Float16)(sh8*L2E), (_Float16)0.0f      };
    float nds = -delta_scale * L2E;          // att = 2^(dt*sigma*nds)

    float t = ckpt[(size_t)ray * NSEG + seg];
    float light = 1.0f;                      // segment-local transmittance
    float o0 = 0.f, o1 = 0.f, o2 = 0.f;

    for (int j = 0; j < SEG_STEPS; ++j) {
        if (t >= tmax) break;
        int flat;
        float dt = march_step(t, ox, oy, oz, dx, dy, dz, idx, idy, idz, &flat);

        // L2-resident occupancy probe: skip empty voxels (bit-exact:
        // sigma<=0 -> att=1, weight=0, light & output unchanged).
        unsigned int mb = occ_mask[flat >> 3];
        if (mb & (1u << (flat & 7))) {
            const uint4* vp = (const uint4*)(vox_grid + (size_t)flat * PAD_DIM);
            Rec rec;
            rec.u[0] = vp[0]; rec.u[1] = vp[1];
            rec.u[2] = vp[2]; rec.u[3] = vp[3];

            float sigma = (float)rec.s[30];          // >0 by mask
            float att = fexp2(dt * sigma * nds);
            float la  = light * att;                 // light AFTER this step
            float w   = light - la;                  // = light*(1-att)
            light = la;

            // r_c pre-scaled by log2(e): sigmoid = rcp(1 + 2^-r)
            float r0 = fdot2(rec.h[ 4], S8z, fdot2(rec.h[ 3], S67,
                       fdot2(rec.h[ 2], S45, fdot2(rec.h[ 1], S23,
                       fdot2(rec.h[ 0], S01, 0.0f)))));
            float r1 = fdot2(rec.h[ 9], S8z, fdot2(rec.h[ 8], S67,
                       fdot2(rec.h[ 7], S45, fdot2(rec.h[ 6], S23,
                       fdot2(rec.h[ 5], S01, 0.0f)))));
            float r2 = fdot2(rec.h[14], S8z, fdot2(rec.h[13], S67,
                       fdot2(rec.h[12], S45, fdot2(rec.h[11], S23,
                       fdot2(rec.h[10], S01, 0.0f)))));

            float g0 = frcp(1.0f + fexp2neg(r0));
            float g1 = frcp(1.0f + fexp2neg(r1));
            float g2 = frcp(1.0f + fexp2neg(r2));

            o0 = fmaf(w, g0, o0);
            o1 = fmaf(w, g1, o1);
            o2 = fmaf(w, g2, o2);
        }
        t += dt;
    }

    // ---- 8-lane combine (lanes 8m..8m+7 hold segments 0..7 of one ray) ----
    float l0 = __shfl(light, 0, 8);
    float l1 = __shfl(light, 1, 8);
    float l2 = __shfl(light, 2, 8);
    float l3 = __shfl(light, 3, 8);
    float l4 = __shfl(light, 4, 8);
    float l5 = __shfl(light, 5, 8);
    float l6 = __shfl(light, 6, 8);
    float l7 = __shfl(light, 7, 8);

    float P = 1.0f;
    if (seg > 0) P *= l0;
    if (seg > 1) P *= l1;
    if (seg > 2) P *= l2;
    if (seg > 3) P *= l3;
    if (seg > 4) P *= l4;
    if (seg > 5) P *= l5;
    if (seg > 6) P *= l6;
    float total_light = l0*l1*l2*l3*l4*l5*l6*l7;

    o0 *= P; o1 *= P; o2 *= P;
    o0 += __shfl_xor(o0, 1, 8); o0 += __shfl_xor(o0, 2, 8); o0 += __shfl_xor(o0, 4, 8);
    o1 += __shfl_xor(o1, 1, 8); o1 += __shfl_xor(o1, 2, 8); o1 += __shfl_xor(o1, 4, 8);
    o2 += __shfl_xor(o2, 1, 8); o2 += __shfl_xor(o2, 2, 8); o2 += __shfl_xor(o2, 4, 8);

    if (seg == 0) {
        out[3*ray+0] = o0 + total_light * BG;
        out[3*ray+1] = o1 + total_light * BG;
        out[3*ray+2] = o2 + total_light * BG;
    }
}

extern "C" void kernel_launch(void* const* d_in, const int* in_sizes, int n_in,
                              void* d_out, int out_size, void* d_ws, size_t ws_size,
                              hipStream_t stream) {
    const float* tree      = (const float*)d_in[0];
    const float* origins   = (const float*)d_in[1];
    const float* dirs      = (const float*)d_in[2];
    const float* viewdirs  = (const float*)d_in[3];
    const float* invradius = (const float*)d_in[4];
    float* out = (float*)d_out;

    int nB   = in_sizes[1] / 3;
    int nvox = in_sizes[0] / DATA_DIM;

    const int block = 256;
    __half* hgrid = (__half*)d_ws;
    float* ckpt = (float*)((char*)d_ws + (size_t)nvox * PAD_DIM * sizeof(__half));
    unsigned char* occ_mask =
        (unsigned char*)((char*)ckpt + (size_t)nB * NSEG * sizeof(float));

    int nGeomB = (nB + block - 1) / block;
    int nConvB = (nvox * 2 + block - 1) / block;
    int nMaskB = ((nvox >> 3) + block - 1) / block;
    prep_kernel<<<nGeomB + nConvB + nMaskB, block, 0, stream>>>(
        tree, hgrid, nvox, origins, dirs, ckpt, occ_mask, nB, nGeomB, nConvB);

    int nmarch = nB * NSEG;
    march_kernel<<<(nmarch + block - 1) / block, block, 0, stream>>>(
        hgrid, occ_mask, origins, dirs, viewdirs, invradius, ckpt, out, nB);
    (void)ws_size;
}